// Round 8
// baseline (358.535 us; speedup 1.0000x reference)
//
#include <hip/hip_runtime.h>

// FastVCompressor: VQ nearest-code + gather + sparsity mask.
//   keys [4,4096,1024] f32, values [4,4096,1024] f32, codebook [256,1024] f32
// out = concat(keys_c, values_c) f32.
//
// R13: barrier-free argmin. Five variants (R5..R12) all plateaued at 85-130us;
//   the invariant was the per-step __syncthreads around the A LDS round-trip.
//   A-fragments are directly loadable from X (lane l, tile i reads
//   X[row0+i*16+(l&15)][s*32+(l>>4)*8..+8] = 2 float4) -> each wave loads+
//   converts its own A (4x redundant VALU, hides under MFMA; X tile L1/L2-
//   shared). B from frag-major wbuf (L2), same-step, covered by the ~700cy
//   convert block. A-raw one-step-ahead reg dbuf covers HBM latency.
//   NO LDS, NO barrier in the K-loop; waves drift freely.
//   Pipeline: prep_all -> argmin -> gather -> recheck (direct out overwrite).

#define H 1024
#define NC 256
#define MT 64
#define THREADS 256
#define BK 32
#define KSTEPS (H / BK)   // 32
#define WLCAP 32768

typedef __attribute__((ext_vector_type(8))) short bf16x8;
typedef __attribute__((ext_vector_type(4))) float f32x4;

static __device__ inline unsigned short f2bf_rne(float f) {
    unsigned u = __float_as_uint(f);
    u += 0x7FFF + ((u >> 16) & 1);
    return (unsigned short)(u >> 16);
}
static __device__ inline float bf2f(unsigned short h) {
    return __uint_as_float((unsigned)h << 16);
}
static __device__ inline void cvt8(const float4 a, const float4 b,
                                   bf16x8& hi8, bf16x8& lo8) {
    const float x[8] = {a.x, a.y, a.z, a.w, b.x, b.y, b.z, b.w};
    unsigned short h[8], l[8];
    #pragma unroll
    for (int j = 0; j < 8; ++j) {
        h[j] = f2bf_rne(x[j]);
        l[j] = f2bf_rne(x[j] - bf2f(h[j]));
    }
    hi8 = *(const bf16x8*)h;
    lo8 = *(const bf16x8*)l;
}

// ---------------- prep_all: c_sq + wt4 + wbuf frag-pack + count zero -------
// One block per code b. Row staged in LDS; each thread then produces one
// wbuf uint4 piece (s = t>>3, kq = (t>>1)&3, h = t&1).
// wt4 layout: float4 index (k>>2)*NC + code  holds cb[code][4k..4k+3].
// wbuf uint4 index: ((s*16 + ct)*2 + h)*64 + kq*16 + (code&15), ct = code>>4.
__global__ __launch_bounds__(256) void prep_all(const float* __restrict__ cb,
                                                float* __restrict__ c_sq,
                                                float4* __restrict__ wt4,
                                                unsigned short* __restrict__ wbuf,
                                                int* __restrict__ wl_count) {
    __shared__ float xs[H];
    __shared__ float red[4];
    const int b = blockIdx.x;
    const int t = threadIdx.x;
    if (b == 0 && t == 0) wl_count[0] = 0;
    const float4 v = *(const float4*)(cb + (size_t)b * H + 4 * t);
    *(float4*)&xs[4 * t] = v;
    wt4[(size_t)t * NC + b] = v;
    float s = v.x * v.x + v.y * v.y + v.z * v.z + v.w * v.w;
    #pragma unroll
    for (int off = 32; off > 0; off >>= 1) s += __shfl_down(s, off);
    if ((t & 63) == 0) red[t >> 6] = s;
    __syncthreads();
    if (t == 0) c_sq[b] = red[0] + red[1] + red[2] + red[3];

    const int sl = t >> 3;
    const int kq = (t >> 1) & 3;
    const int h = t & 1;
    const int k0 = sl * BK + kq * 8;
    unsigned short o[8];
    #pragma unroll
    for (int j = 0; j < 8; ++j) {
        const float x = xs[k0 + j];
        const unsigned short hi = f2bf_rne(x);
        o[j] = h ? f2bf_rne(x - bf2f(hi)) : hi;
    }
    const size_t idx = (((size_t)sl * 16 + (b >> 4)) * 2 + h) * 64 + kq * 16 + (b & 15);
    *(uint4*)(wbuf + idx * 8) = *(const uint4*)o;
}

// ---------------- main: GEMM-argmin, barrier-free, all operands via regs ----
__global__ __launch_bounds__(THREADS, 2) void argmin_kernel(
    const float* __restrict__ keys, const float* __restrict__ vals,
    const unsigned short* __restrict__ wbuf, const float* __restrict__ c_sq,
    int* __restrict__ fidx_g, int* __restrict__ wl, int* __restrict__ wl_count) {
    __shared__ float sred[768];      // 3 KB epilogue scratch only

    const int t = threadIdx.x;
    const int lane = t & 63;
    const int w = t >> 6;            // wave 0..3: code-quad ct = w*4+j
    const int tensor = blockIdx.y;
    const float* __restrict__ X = tensor ? vals : keys;
    const int row0 = blockIdx.x * MT;
    const uint4* __restrict__ wb4 = (const uint4*)wbuf;

    // per-lane A base: row = row0 + (lane&15) (+ i*16), k = (lane>>4)*8 (+ s*32)
    const float* __restrict__ abase =
        X + (size_t)(row0 + (lane & 15)) * H + (lane >> 4) * 8;

    f32x4 acc[4][4];
    #pragma unroll
    for (int i = 0; i < 4; ++i)
        #pragma unroll
        for (int j = 0; j < 4; ++j) acc[i][j] = (f32x4){0.f, 0.f, 0.f, 0.f};

    float4 araw[2][4][2];
    // ---- prologue: load A-raw step 0 into buf 0 ----
    #pragma unroll
    for (int i = 0; i < 4; ++i) {
        araw[0][i][0] = *(const float4*)(abase + (size_t)i * 16 * H);
        araw[0][i][1] = *(const float4*)(abase + (size_t)i * 16 * H + 4);
    }

    #pragma unroll 2
    for (int s = 0; s < KSTEPS; ++s) {
        const int p = s & 1;
        // 1) issue A-raw loads for step s+1 (HBM/L3; covered by full step)
        if (s + 1 < KSTEPS) {
            #pragma unroll
            for (int i = 0; i < 4; ++i) {
                araw[p ^ 1][i][0] = *(const float4*)(abase + (size_t)i * 16 * H + (s + 1) * BK);
                araw[p ^ 1][i][1] = *(const float4*)(abase + (size_t)i * 16 * H + (s + 1) * BK + 4);
            }
        }
        // 2) issue B loads for step s (L2; covered by the convert block below)
        bf16x8 bh[4], bl[4];
        {
            const uint4* bsrc = wb4 + (size_t)s * 2048 + (size_t)(w * 4) * 128 + lane;
            #pragma unroll
            for (int j = 0; j < 4; ++j) {
                bh[j] = *(const bf16x8*)(bsrc + j * 128);
                bl[j] = *(const bf16x8*)(bsrc + j * 128 + 64);
            }
        }
        // 3) convert A-raw[s] -> fragments (long VALU block, hides B latency)
        bf16x8 ah[4], al[4];
        #pragma unroll
        for (int i = 0; i < 4; ++i)
            cvt8(araw[p][i][0], araw[p][i][1], ah[i], al[i]);
        // 4) MFMA
        #pragma unroll
        for (int i = 0; i < 4; ++i)
            #pragma unroll
            for (int j = 0; j < 4; ++j) {
                acc[i][j] = __builtin_amdgcn_mfma_f32_16x16x32_bf16(ah[i], bl[j], acc[i][j], 0, 0, 0);
                acc[i][j] = __builtin_amdgcn_mfma_f32_16x16x32_bf16(al[i], bh[j], acc[i][j], 0, 0, 0);
                acc[i][j] = __builtin_amdgcn_mfma_f32_16x16x32_bf16(ah[i], bh[j], acc[i][j], 0, 0, 0);
            }
    }

    // ---- per-row argmin with best-2 tracking ----
    float csq[4];
    #pragma unroll
    for (int j = 0; j < 4; ++j) csq[j] = c_sq[w * 64 + j * 16 + (lane & 15)];

    float* rv = sred;          // [64][4]
    int* ri = (int*)sred + 256;  // [64][4]
    float* r2 = sred + 512;    // [64][4]

    #pragma unroll
    for (int i = 0; i < 4; ++i) {
        #pragma unroll
        for (int r = 0; r < 4; ++r) {
            const int row = i * 16 + (lane >> 4) * 4 + r;
            float bv = csq[0] - 2.0f * acc[i][0][r];
            int bc = w * 64 + (lane & 15);
            float b2 = 3.4e38f;
            #pragma unroll
            for (int j = 1; j < 4; ++j) {
                const float v = csq[j] - 2.0f * acc[i][j][r];
                if (v < bv) { b2 = bv; bv = v; bc = w * 64 + j * 16 + (lane & 15); }
                else b2 = fminf(b2, v);
            }
            #pragma unroll
            for (int off = 1; off < 16; off <<= 1) {
                const float ov = __shfl_xor(bv, off);
                const int oc = __shfl_xor(bc, off);
                const float ov2 = __shfl_xor(b2, off);
                const float nb2 = fminf(fmaxf(bv, ov), fminf(b2, ov2));
                if (ov < bv || (ov == bv && oc < bc)) { bv = ov; bc = oc; }
                b2 = nb2;
            }
            if ((lane & 15) == 0) {
                rv[row * 4 + w] = bv;
                ri[row * 4 + w] = bc;
                r2[row * 4 + w] = b2;
            }
        }
    }
    __syncthreads();
    if (t < MT) {
        float bv = rv[t * 4];
        int bc = ri[t * 4];
        float b2 = r2[t * 4];
        #pragma unroll
        for (int g = 1; g < 4; ++g) {        // ascending wave = ascending codes
            const float v = rv[t * 4 + g];
            const int c = ri[t * 4 + g];
            const float v2 = r2[t * 4 + g];
            const float nb2 = fminf(fmaxf(bv, v), fminf(b2, v2));
            if (v < bv || (v == bv && c < bc)) { bv = v; bc = c; }
            b2 = nb2;
        }
        const size_t rowg = (size_t)tensor * (gridDim.x * MT) + row0 + t;
        fidx_g[rowg] = bc;
        if (b2 - bv < 0.15f) {
            const int pos = atomicAdd(wl_count, 1);
            if (pos < WLCAP) wl[pos] = (int)rowg;
        }
    }
}

// ---------------- gather ----------------
__global__ __launch_bounds__(256) void gather_kernel(
    const float* __restrict__ cb, const float* __restrict__ c_sq,
    const int* __restrict__ fidx_g, float* __restrict__ out) {
    const int t = threadIdx.x;
    const int row = blockIdx.x * 4 + (t >> 6);
    const int lane = t & 63;
    const int ci = fidx_g[row];
    const float m = (c_sq[ci] > 0.01f) ? 1.0f : 0.0f;
    const float4* __restrict__ src = (const float4*)(cb + (size_t)ci * H);
    float4* __restrict__ dst = (float4*)(out + (size_t)row * H);
    #pragma unroll
    for (int j = 0; j < 4; ++j) {
        float4 v = src[lane + 64 * j];
        v.x *= m; v.y *= m; v.z *= m; v.w *= m;
        dst[lane + 64 * j] = v;
    }
}

// ---------------- exact fp64 recheck of worklist rows, writes out directly ---
__global__ __launch_bounds__(256) void recheck_kernel(
    const float* __restrict__ keys, const float* __restrict__ vals,
    const float4* __restrict__ wt4, const float* __restrict__ c_sq,
    const float* __restrict__ cb, const int* __restrict__ wl,
    const int* __restrict__ wl_count, float* __restrict__ out) {
    __shared__ float xs[4][H];       // 16 KB
    __shared__ double bvs[16];
    __shared__ int bcs[16];
    __shared__ int bcf[4];

    const int t = threadIdx.x;
    const int w = t >> 6;
    const int lane = t & 63;
    int n = wl_count[0];
    if (n > WLCAP) n = WLCAP;
    if (n == 0) return;

    for (int base = blockIdx.x * 4; base < n; base += gridDim.x * 4) {
        // wave w loads row (base + w); clamp duplicates are computed but not written
        {
            const int idx = base + w;
            const int rowg = wl[idx < n ? idx : n - 1];
            const float* __restrict__ X =
                ((rowg >> 14) ? vals : keys) + (size_t)(rowg & 16383) * H;
            #pragma unroll
            for (int j = 0; j < 4; ++j)
                ((float4*)&xs[w][0])[lane + 64 * j] = ((const float4*)X)[lane + 64 * j];
        }
        __syncthreads();

        double dd0 = 0.0, dd1 = 0.0, dd2 = 0.0, dd3 = 0.0;
        for (int k0 = 0; k0 < H; k0 += 4) {
            const float4 wv = wt4[(size_t)(k0 >> 2) * NC + t];
            const float4 x0 = *(const float4*)&xs[0][k0];
            const float4 x1 = *(const float4*)&xs[1][k0];
            const float4 x2 = *(const float4*)&xs[2][k0];
            const float4 x3 = *(const float4*)&xs[3][k0];
            dd0 = fma((double)x0.x, (double)wv.x, dd0);
            dd0 = fma((double)x0.y, (double)wv.y, dd0);
            dd0 = fma((double)x0.z, (double)wv.z, dd0);
            dd0 = fma((double)x0.w, (double)wv.w, dd0);
            dd1 = fma((double)x1.x, (double)wv.x, dd1);
            dd1 = fma((double)x1.y, (double)wv.y, dd1);
            dd1 = fma((double)x1.z, (double)wv.z, dd1);
            dd1 = fma((double)x1.w, (double)wv.w, dd1);
            dd2 = fma((double)x2.x, (double)wv.x, dd2);
            dd2 = fma((double)x2.y, (double)wv.y, dd2);
            dd2 = fma((double)x2.z, (double)wv.z, dd2);
            dd2 = fma((double)x2.w, (double)wv.w, dd2);
            dd3 = fma((double)x3.x, (double)wv.x, dd3);
            dd3 = fma((double)x3.y, (double)wv.y, dd3);
            dd3 = fma((double)x3.z, (double)wv.z, dd3);
            dd3 = fma((double)x3.w, (double)wv.w, dd3);
        }

        const double csqt = (double)c_sq[t];
        const double dv[4] = {dd0, dd1, dd2, dd3};
        #pragma unroll
        for (int r = 0; r < 4; ++r) {
            double bv = csqt - 2.0 * dv[r];
            int bc = t;
            #pragma unroll
            for (int off = 1; off < 64; off <<= 1) {
                const double ov = __shfl_xor(bv, off);
                const int oc = __shfl_xor(bc, off);
                if (ov < bv || (ov == bv && oc < bc)) { bv = ov; bc = oc; }
            }
            if (lane == 0) { bvs[r * 4 + w] = bv; bcs[r * 4 + w] = bc; }
        }
        __syncthreads();
        if (t < 4) {
            double bv = bvs[t * 4];
            int bc = bcs[t * 4];
            #pragma unroll
            for (int g = 1; g < 4; ++g) {   // ascending wave = ascending codes
                const double v = bvs[t * 4 + g];
                const int c = bcs[t * 4 + g];
                if (v < bv || (v == bv && c < bc)) { bv = v; bc = c; }
            }
            bcf[t] = bc;
        }
        __syncthreads();
        // write corrected output rows directly
        #pragma unroll
        for (int r = 0; r < 4; ++r) {
            const int idx = base + r;
            if (idx < n) {
                const int bc = bcf[r];
                const int rowg = wl[idx];
                const float m = (c_sq[bc] > 0.01f) ? 1.0f : 0.0f;
                float4 v = ((const float4*)(cb + (size_t)bc * H))[t];
                v.x *= m; v.y *= m; v.z *= m; v.w *= m;
                ((float4*)(out + (size_t)rowg * H))[t] = v;
            }
        }
        __syncthreads();
    }
}

extern "C" void kernel_launch(void* const* d_in, const int* in_sizes, int n_in,
                              void* d_out, int out_size, void* d_ws, size_t ws_size,
                              hipStream_t stream) {
    const float* keys = (const float*)d_in[0];
    const float* vals = (const float*)d_in[1];
    const float* cb   = (const float*)d_in[2];
    float* out = (float*)d_out;

    // ws: c_sq[256] f32 | wt4[256K f32, packed-k float4] | wbuf[512K] u16
    //     | fidx[32K] i32 | wl[32K] i32 | wl_count[1]
    float* c_sq = (float*)d_ws;
    float4* wt4 = (float4*)(c_sq + NC);
    unsigned short* wbuf = (unsigned short*)((float*)wt4 + (size_t)H * NC);
    int* fidx_g = (int*)(wbuf + (size_t)KSTEPS * 2048 * 8);
    int* wl = fidx_g + 32768;
    int* wl_count = wl + WLCAP;

    const int rows = in_sizes[0] / H;  // 16384 per tensor

    prep_all<<<NC, 256, 0, stream>>>(cb, c_sq, wt4, wbuf, wl_count);
    dim3 g(rows / MT, 2);
    argmin_kernel<<<g, THREADS, 0, stream>>>(keys, vals, wbuf, c_sq, fidx_g, wl, wl_count);
    gather_kernel<<<rows * 2 / 4, 256, 0, stream>>>(cb, c_sq, fidx_g, out);
    recheck_kernel<<<1024, 256, 0, stream>>>(keys, vals, wt4, c_sq, cb, wl, wl_count, out);
}

// Round 9
// 321.475 us; speedup vs baseline: 1.1153x; 1.1153x over previous
//
#include <hip/hip_runtime.h>

// FastVCompressor: VQ nearest-code + gather + sparsity mask.
//   keys [4,4096,1024] f32, values [4,4096,1024] f32, codebook [256,1024] f32
// out = concat(keys_c, values_c) f32.
//
// R14 = R12 + counted-wait barrier (T4-lite). Single change:
//   __syncthreads() in the K-loop compiles to s_waitcnt vmcnt(0) lgkmcnt(0);
//   s_barrier — draining the in-flight A-raw HBM prefetch (s+2) and B L2
//   prefetch (s+1) EVERY step. The barrier's only correctness job is the
//   LDS A-dbuf ordering, so: s_waitcnt lgkmcnt(0) + raw s_barrier, vmcnt
//   NOT drained -> prefetches stay in flight across the barrier (AITER
//   pattern). sched_barrier(0) fences per guide rule #18.
//   Rest identical to R12: B reg-dbuf from L2 (frag-major wbuf), A LDS dbuf
//   (conflict-free), 4 waves, 16KB LDS.
//   Pipeline: prep_all -> argmin -> gather -> recheck (direct out overwrite).

#define H 1024
#define NC 256
#define MT 64
#define THREADS 256
#define BK 32
#define KSTEPS (H / BK)   // 32
#define WLCAP 32768

typedef __attribute__((ext_vector_type(8))) short bf16x8;
typedef __attribute__((ext_vector_type(4))) float f32x4;

static __device__ inline unsigned short f2bf_rne(float f) {
    unsigned u = __float_as_uint(f);
    u += 0x7FFF + ((u >> 16) & 1);
    return (unsigned short)(u >> 16);
}
static __device__ inline float bf2f(unsigned short h) {
    return __uint_as_float((unsigned)h << 16);
}

// ---------------- prep_all: c_sq + wt4 + wbuf frag-pack + count zero -------
// One block per code b. Row staged in LDS; each thread then produces one
// wbuf uint4 piece (s = t>>3, kq = (t>>1)&3, h = t&1).
// wt4 layout: float4 index (k>>2)*NC + code  holds cb[code][4k..4k+3].
// wbuf uint4 index: ((s*16 + ct)*2 + h)*64 + kq*16 + (code&15), ct = code>>4.
__global__ __launch_bounds__(256) void prep_all(const float* __restrict__ cb,
                                                float* __restrict__ c_sq,
                                                float4* __restrict__ wt4,
                                                unsigned short* __restrict__ wbuf,
                                                int* __restrict__ wl_count) {
    __shared__ float xs[H];
    __shared__ float red[4];
    const int b = blockIdx.x;
    const int t = threadIdx.x;
    if (b == 0 && t == 0) wl_count[0] = 0;
    const float4 v = *(const float4*)(cb + (size_t)b * H + 4 * t);
    *(float4*)&xs[4 * t] = v;
    wt4[(size_t)t * NC + b] = v;
    float s = v.x * v.x + v.y * v.y + v.z * v.z + v.w * v.w;
    #pragma unroll
    for (int off = 32; off > 0; off >>= 1) s += __shfl_down(s, off);
    if ((t & 63) == 0) red[t >> 6] = s;
    __syncthreads();
    if (t == 0) c_sq[b] = red[0] + red[1] + red[2] + red[3];

    const int sl = t >> 3;
    const int kq = (t >> 1) & 3;
    const int h = t & 1;
    const int k0 = sl * BK + kq * 8;
    unsigned short o[8];
    #pragma unroll
    for (int j = 0; j < 8; ++j) {
        const float x = xs[k0 + j];
        const unsigned short hi = f2bf_rne(x);
        o[j] = h ? f2bf_rne(x - bf2f(hi)) : hi;
    }
    const size_t idx = (((size_t)sl * 16 + (b >> 4)) * 2 + h) * 64 + kq * 16 + (b & 15);
    *(uint4*)(wbuf + idx * 8) = *(const uint4*)o;
}

// ---------------- main: GEMM-argmin, B reg-dbuf, counted-wait barrier ------
__global__ __launch_bounds__(THREADS, 2) void argmin_kernel(
    const float* __restrict__ keys, const float* __restrict__ vals,
    const unsigned short* __restrict__ wbuf, const float* __restrict__ c_sq,
    int* __restrict__ fidx_g, int* __restrict__ wl, int* __restrict__ wl_count) {
    __shared__ uint4 a_u4[2][512];    // 16 KB: A dbuf, (rt*2+h)*64 + slot

    const int t = threadIdx.x;
    const int lane = t & 63;
    const int w = t >> 6;            // wave 0..3: code-quad ct = w*4+j
    const int tensor = blockIdx.y;
    const float* __restrict__ X = tensor ? vals : keys;
    const int row0 = blockIdx.x * MT;
    const uint4* __restrict__ wb4 = (const uint4*)wbuf;

    // A staging slot: thread t stages (rt = t>>6, slot = lane)
    const int s_row = row0 + (t >> 6) * 16 + (lane & 15);
    const int s_kq = (lane >> 4) * 8;
    const float* __restrict__ xrow = X + (size_t)s_row * H + s_kq;

    f32x4 acc[4][4];
    #pragma unroll
    for (int i = 0; i < 4; ++i)
        #pragma unroll
        for (int j = 0; j < 4; ++j) acc[i][j] = (f32x4){0.f, 0.f, 0.f, 0.f};

    bf16x8 bh[2][4], bl[2][4];

    // ---- prologue: stage A step 0, load B[0] into reg buf 0 ----
    {
        const float4 c0 = *(const float4*)(xrow);
        const float4 c1 = *(const float4*)(xrow + 4);
        float x[8] = {c0.x, c0.y, c0.z, c0.w, c1.x, c1.y, c1.z, c1.w};
        unsigned short hi[8], lo[8];
        #pragma unroll
        for (int j = 0; j < 8; ++j) {
            hi[j] = f2bf_rne(x[j]);
            lo[j] = f2bf_rne(x[j] - bf2f(hi[j]));
        }
        a_u4[0][((t >> 6) * 2 + 0) * 64 + lane] = *(const uint4*)hi;
        a_u4[0][((t >> 6) * 2 + 1) * 64 + lane] = *(const uint4*)lo;
        const uint4* bsrc = wb4 + (size_t)(w * 4) * 128 + lane;
        #pragma unroll
        for (int j = 0; j < 4; ++j) {
            bh[0][j] = *(const bf16x8*)(bsrc + j * 128);
            bl[0][j] = *(const bf16x8*)(bsrc + j * 128 + 64);
        }
    }
    float4 nx0 = *(const float4*)(xrow + BK);
    float4 nx1 = *(const float4*)(xrow + BK + 4);
    __syncthreads();

    #pragma unroll 2
    for (int s = 0; s < KSTEPS; ++s) {
        const int p = s & 1;
        if (s + 1 < KSTEPS) {
            // issue B[s+1] loads FIRST (async, land in reg buf p^1)
            const uint4* bsrc = wb4 + (size_t)(s + 1) * 2048 + (size_t)(w * 4) * 128 + lane;
            #pragma unroll
            for (int j = 0; j < 4; ++j) {
                bh[p ^ 1][j] = *(const bf16x8*)(bsrc + j * 128);
                bl[p ^ 1][j] = *(const bf16x8*)(bsrc + j * 128 + 64);
            }
            // stage A step s+1 into LDS buffer p^1 (stale since end of step s-1)
            float x[8] = {nx0.x, nx0.y, nx0.z, nx0.w, nx1.x, nx1.y, nx1.z, nx1.w};
            unsigned short hi[8], lo[8];
            #pragma unroll
            for (int j = 0; j < 8; ++j) {
                hi[j] = f2bf_rne(x[j]);
                lo[j] = f2bf_rne(x[j] - bf2f(hi[j]));
            }
            a_u4[p ^ 1][((t >> 6) * 2 + 0) * 64 + lane] = *(const uint4*)hi;
            a_u4[p ^ 1][((t >> 6) * 2 + 1) * 64 + lane] = *(const uint4*)lo;
        }
        if (s + 2 < KSTEPS) {
            nx0 = *(const float4*)(xrow + (s + 2) * BK);
            nx1 = *(const float4*)(xrow + (s + 2) * BK + 4);
        }
        // compute on A LDS buffer p, B reg buffer p
        bf16x8 ah[4], al[4];
        #pragma unroll
        for (int i = 0; i < 4; ++i) {
            ah[i] = ((const bf16x8*)&a_u4[p][0])[(i * 2 + 0) * 64 + lane];
            al[i] = ((const bf16x8*)&a_u4[p][0])[(i * 2 + 1) * 64 + lane];
        }
        #pragma unroll
        for (int i = 0; i < 4; ++i)
            #pragma unroll
            for (int j = 0; j < 4; ++j) {
                acc[i][j] = __builtin_amdgcn_mfma_f32_16x16x32_bf16(ah[i], bl[p][j], acc[i][j], 0, 0, 0);
                acc[i][j] = __builtin_amdgcn_mfma_f32_16x16x32_bf16(al[i], bh[p][j], acc[i][j], 0, 0, 0);
                acc[i][j] = __builtin_amdgcn_mfma_f32_16x16x32_bf16(ah[i], bh[p][j], acc[i][j], 0, 0, 0);
            }
        // counted-wait barrier: only LDS ordering is cross-wave; vmcnt NOT
        // drained -> A/B prefetch loads stay in flight across the barrier.
        asm volatile("s_waitcnt lgkmcnt(0)" ::: "memory");
        __builtin_amdgcn_sched_barrier(0);
        __builtin_amdgcn_s_barrier();
        __builtin_amdgcn_sched_barrier(0);
    }

    // ---- per-row argmin with best-2 tracking ----
    float csq[4];
    #pragma unroll
    for (int j = 0; j < 4; ++j) csq[j] = c_sq[w * 64 + j * 16 + (lane & 15)];

    float* rv = (float*)&a_u4[0][0];        // [64][4]
    int* ri = (int*)&a_u4[0][0] + 256;      // [64][4]
    float* r2 = (float*)&a_u4[0][0] + 512;  // [64][4]

    #pragma unroll
    for (int i = 0; i < 4; ++i) {
        #pragma unroll
        for (int r = 0; r < 4; ++r) {
            const int row = i * 16 + (lane >> 4) * 4 + r;
            float bv = csq[0] - 2.0f * acc[i][0][r];
            int bc = w * 64 + (lane & 15);
            float b2 = 3.4e38f;
            #pragma unroll
            for (int j = 1; j < 4; ++j) {
                const float v = csq[j] - 2.0f * acc[i][j][r];
                if (v < bv) { b2 = bv; bv = v; bc = w * 64 + j * 16 + (lane & 15); }
                else b2 = fminf(b2, v);
            }
            #pragma unroll
            for (int off = 1; off < 16; off <<= 1) {
                const float ov = __shfl_xor(bv, off);
                const int oc = __shfl_xor(bc, off);
                const float ov2 = __shfl_xor(b2, off);
                const float nb2 = fminf(fmaxf(bv, ov), fminf(b2, ov2));
                if (ov < bv || (ov == bv && oc < bc)) { bv = ov; bc = oc; }
                b2 = nb2;
            }
            if ((lane & 15) == 0) {
                rv[row * 4 + w] = bv;
                ri[row * 4 + w] = bc;
                r2[row * 4 + w] = b2;
            }
        }
    }
    __syncthreads();
    if (t < MT) {
        float bv = rv[t * 4];
        int bc = ri[t * 4];
        float b2 = r2[t * 4];
        #pragma unroll
        for (int g = 1; g < 4; ++g) {        // ascending wave = ascending codes
            const float v = rv[t * 4 + g];
            const int c = ri[t * 4 + g];
            const float v2 = r2[t * 4 + g];
            const float nb2 = fminf(fmaxf(bv, v), fminf(b2, v2));
            if (v < bv || (v == bv && c < bc)) { bv = v; bc = c; }
            b2 = nb2;
        }
        const size_t rowg = (size_t)tensor * (gridDim.x * MT) + row0 + t;
        fidx_g[rowg] = bc;
        if (b2 - bv < 0.15f) {
            const int pos = atomicAdd(wl_count, 1);
            if (pos < WLCAP) wl[pos] = (int)rowg;
        }
    }
}

// ---------------- gather ----------------
__global__ __launch_bounds__(256) void gather_kernel(
    const float* __restrict__ cb, const float* __restrict__ c_sq,
    const int* __restrict__ fidx_g, float* __restrict__ out) {
    const int t = threadIdx.x;
    const int row = blockIdx.x * 4 + (t >> 6);
    const int lane = t & 63;
    const int ci = fidx_g[row];
    const float m = (c_sq[ci] > 0.01f) ? 1.0f : 0.0f;
    const float4* __restrict__ src = (const float4*)(cb + (size_t)ci * H);
    float4* __restrict__ dst = (float4*)(out + (size_t)row * H);
    #pragma unroll
    for (int j = 0; j < 4; ++j) {
        float4 v = src[lane + 64 * j];
        v.x *= m; v.y *= m; v.z *= m; v.w *= m;
        dst[lane + 64 * j] = v;
    }
}

// ---------------- exact fp64 recheck of worklist rows, writes out directly ---
__global__ __launch_bounds__(256) void recheck_kernel(
    const float* __restrict__ keys, const float* __restrict__ vals,
    const float4* __restrict__ wt4, const float* __restrict__ c_sq,
    const float* __restrict__ cb, const int* __restrict__ wl,
    const int* __restrict__ wl_count, float* __restrict__ out) {
    __shared__ float xs[4][H];       // 16 KB
    __shared__ double bvs[16];
    __shared__ int bcs[16];
    __shared__ int bcf[4];

    const int t = threadIdx.x;
    const int w = t >> 6;
    const int lane = t & 63;
    int n = wl_count[0];
    if (n > WLCAP) n = WLCAP;
    if (n == 0) return;

    for (int base = blockIdx.x * 4; base < n; base += gridDim.x * 4) {
        // wave w loads row (base + w); clamp duplicates are computed but not written
        {
            const int idx = base + w;
            const int rowg = wl[idx < n ? idx : n - 1];
            const float* __restrict__ X =
                ((rowg >> 14) ? vals : keys) + (size_t)(rowg & 16383) * H;
            #pragma unroll
            for (int j = 0; j < 4; ++j)
                ((float4*)&xs[w][0])[lane + 64 * j] = ((const float4*)X)[lane + 64 * j];
        }
        __syncthreads();

        double dd0 = 0.0, dd1 = 0.0, dd2 = 0.0, dd3 = 0.0;
        for (int k0 = 0; k0 < H; k0 += 4) {
            const float4 wv = wt4[(size_t)(k0 >> 2) * NC + t];
            const float4 x0 = *(const float4*)&xs[0][k0];
            const float4 x1 = *(const float4*)&xs[1][k0];
            const float4 x2 = *(const float4*)&xs[2][k0];
            const float4 x3 = *(const float4*)&xs[3][k0];
            dd0 = fma((double)x0.x, (double)wv.x, dd0);
            dd0 = fma((double)x0.y, (double)wv.y, dd0);
            dd0 = fma((double)x0.z, (double)wv.z, dd0);
            dd0 = fma((double)x0.w, (double)wv.w, dd0);
            dd1 = fma((double)x1.x, (double)wv.x, dd1);
            dd1 = fma((double)x1.y, (double)wv.y, dd1);
            dd1 = fma((double)x1.z, (double)wv.z, dd1);
            dd1 = fma((double)x1.w, (double)wv.w, dd1);
            dd2 = fma((double)x2.x, (double)wv.x, dd2);
            dd2 = fma((double)x2.y, (double)wv.y, dd2);
            dd2 = fma((double)x2.z, (double)wv.z, dd2);
            dd2 = fma((double)x2.w, (double)wv.w, dd2);
            dd3 = fma((double)x3.x, (double)wv.x, dd3);
            dd3 = fma((double)x3.y, (double)wv.y, dd3);
            dd3 = fma((double)x3.z, (double)wv.z, dd3);
            dd3 = fma((double)x3.w, (double)wv.w, dd3);
        }

        const double csqt = (double)c_sq[t];
        const double dv[4] = {dd0, dd1, dd2, dd3};
        #pragma unroll
        for (int r = 0; r < 4; ++r) {
            double bv = csqt - 2.0 * dv[r];
            int bc = t;
            #pragma unroll
            for (int off = 1; off < 64; off <<= 1) {
                const double ov = __shfl_xor(bv, off);
                const int oc = __shfl_xor(bc, off);
                if (ov < bv || (ov == bv && oc < bc)) { bv = ov; bc = oc; }
            }
            if (lane == 0) { bvs[r * 4 + w] = bv; bcs[r * 4 + w] = bc; }
        }
        __syncthreads();
        if (t < 4) {
            double bv = bvs[t * 4];
            int bc = bcs[t * 4];
            #pragma unroll
            for (int g = 1; g < 4; ++g) {   // ascending wave = ascending codes
                const double v = bvs[t * 4 + g];
                const int c = bcs[t * 4 + g];
                if (v < bv || (v == bv && c < bc)) { bv = v; bc = c; }
            }
            bcf[t] = bc;
        }
        __syncthreads();
        // write corrected output rows directly
        #pragma unroll
        for (int r = 0; r < 4; ++r) {
            const int idx = base + r;
            if (idx < n) {
                const int bc = bcf[r];
                const int rowg = wl[idx];
                const float m = (c_sq[bc] > 0.01f) ? 1.0f : 0.0f;
                float4 v = ((const float4*)(cb + (size_t)bc * H))[t];
                v.x *= m; v.y *= m; v.z *= m; v.w *= m;
                ((float4*)(out + (size_t)rowg * H))[t] = v;
            }
        }
        __syncthreads();
    }
}

extern "C" void kernel_launch(void* const* d_in, const int* in_sizes, int n_in,
                              void* d_out, int out_size, void* d_ws, size_t ws_size,
                              hipStream_t stream) {
    const float* keys = (const float*)d_in[0];
    const float* vals = (const float*)d_in[1];
    const float* cb   = (const float*)d_in[2];
    float* out = (float*)d_out;

    // ws: c_sq[256] f32 | wt4[256K f32, packed-k float4] | wbuf[512K] u16
    //     | fidx[32K] i32 | wl[32K] i32 | wl_count[1]
    float* c_sq = (float*)d_ws;
    float4* wt4 = (float4*)(c_sq + NC);
    unsigned short* wbuf = (unsigned short*)((float*)wt4 + (size_t)H * NC);
    int* fidx_g = (int*)(wbuf + (size_t)KSTEPS * 2048 * 8);
    int* wl = fidx_g + 32768;
    int* wl_count = wl + WLCAP;

    const int rows = in_sizes[0] / H;  // 16384 per tensor

    prep_all<<<NC, 256, 0, stream>>>(cb, c_sq, wt4, wbuf, wl_count);
    dim3 g(rows / MT, 2);
    argmin_kernel<<<g, THREADS, 0, stream>>>(keys, vals, wbuf, c_sq, fidx_g, wl, wl_count);
    gather_kernel<<<rows * 2 / 4, 256, 0, stream>>>(cb, c_sq, fidx_g, out);
    recheck_kernel<<<1024, 256, 0, stream>>>(keys, vals, wt4, c_sq, cb, wl, wl_count, out);
}